// Round 13
// baseline (202.943 us; speedup 1.0000x reference)
//
#include <hip/hip_runtime.h>
#include <hip/hip_bf16.h>
#include <math.h>

// Problem constants
#define B_   512
#define KEV  64
#define NN   1024
#define DD   128
#define EE_  1024
#define HH   256
#define PP   12

typedef __bf16 bf16x8 __attribute__((ext_vector_type(8)));
typedef float  f32x4  __attribute__((ext_vector_type(4)));

static __device__ __forceinline__ unsigned short f2bf(float f) {
    unsigned int u = __builtin_bit_cast(unsigned int, f);
    u = (u + 0x7FFFu + ((u >> 16) & 1u)) >> 16;   // RNE
    return (unsigned short)u;
}

// HW packed f32->bf16 (RNE): 4 instructions per 8 elements
static __device__ __forceinline__ bf16x8 cvt8(f32x4 lo, f32x4 hi) {
    unsigned int r0, r1, r2, r3;
    asm("v_cvt_pk_bf16_f32 %0, %1, %2" : "=v"(r0) : "v"(lo[0]), "v"(lo[1]));
    asm("v_cvt_pk_bf16_f32 %0, %1, %2" : "=v"(r1) : "v"(lo[2]), "v"(lo[3]));
    asm("v_cvt_pk_bf16_f32 %0, %1, %2" : "=v"(r2) : "v"(hi[0]), "v"(hi[1]));
    asm("v_cvt_pk_bf16_f32 %0, %1, %2" : "=v"(r3) : "v"(hi[2]), "v"(hi[3]));
    union { unsigned int u[4]; bf16x8 v; } o;
    o.u[0] = r0; o.u[1] = r1; o.u[2] = r2; o.u[3] = r3;
    return o.v;
}

// ---------------------------------------------------------------------------
// prep (blocks 0..255): W_t f32 -> bf16.  block 256: detect dtypes + build Wc.
//   flags[0] = event_idx is int64 (1) or int32 (0)
//   flags[1] = event_mask repr: 0=uint8, 1=int32, 2=int64
// ---------------------------------------------------------------------------
__global__ __launch_bounds__(256) void prep_kernel(
    const float* __restrict__ Wt,
    const float* __restrict__ Wmm,
    const float* __restrict__ Wts,
    const unsigned int* __restrict__ idxW,
    const unsigned int* __restrict__ mskW,
    unsigned short* __restrict__ WtBf,
    float* __restrict__ Wc,
    int* __restrict__ flags)
{
    if (blockIdx.x < 256) {
        int i4 = (blockIdx.x * 256 + threadIdx.x) * 4;
        const float4 v = *reinterpret_cast<const float4*>(Wt + i4);
        ushort4 o = make_ushort4(f2bf(v.x), f2bf(v.y), f2bf(v.z), f2bf(v.w));
        *reinterpret_cast<ushort4*>(WtBf + i4) = o;
        return;
    }
    __shared__ int any_nz;
    if (threadIdx.x == 0) any_nz = 0;
    __syncthreads();
    int local = 0;
    for (int k = threadIdx.x; k < (B_ * KEV) / 2; k += 256)
        local |= (idxW[2 * k + 1] != 0u);
    if (local) atomicOr(&any_nz, 1);
    for (int k = threadIdx.x; k < PP * DD; k += 256) {
        int p = k >> 7, d = k & 127;
        Wc[k] = Wmm[p * (HH + DD) + HH + d] + Wts[p * DD + d];
    }
    __syncthreads();
    if (threadIdx.x == 0) {
        flags[0] = any_nz ? 0 : 1;                 // 1 => idx is int64
        unsigned int w0 = mskW[0], w1 = mskW[1];
        flags[1] = (w0 == 0x01010101u) ? 0 : ((w1 == 0u) ? 2 : 1);
    }
}

// ---------------------------------------------------------------------------
// event path, LDS-FREE: A-fragments load DIRECTLY from the gathered table
// rows (lane (lm,lg) reads rows mi*16+lm, elements ks*32+lg*8..+8 = 32B
// contiguous; every 64B line fetched exactly once) and convert in-register
// via v_cvt_pk_bf16_f32.  No staging LDS, no barriers, no vmcnt coupling in
// the K-loop — the compiler software-pipelines loads across ks freely.
// A-data is use-once (staging it was pure overhead).  B-frags from
// L2-resident WtBf.  MFMA fragment layout identical to the proven kernels.
// ---------------------------------------------------------------------------
__global__ __launch_bounds__(256, 2) void event_kernel(
    const float* __restrict__ table,
    const void* __restrict__ idxRaw,
    const void* __restrict__ maskRaw,
    const int* __restrict__ flags,
    const unsigned short* __restrict__ WtBf,
    const float* __restrict__ bt,
    const float* __restrict__ Wmm,
    const float* __restrict__ bmm,
    const float* __restrict__ bts,
    float* __restrict__ cOut)
{
    const int b = blockIdx.x;
    const int t = threadIdx.x;
    const int w = t >> 6;        // wave id: owns h-block [w*64, w*64+64)
    const int l = t & 63;        // lane
    const int lm = l & 15;
    const int lg = l >> 4;

    __shared__ int           sIdx[KEV];
    __shared__ unsigned char sMask[KEV];
    __shared__ float         sEv[HH];

    if (t < KEV) {
        const int i = b * KEV + t;
        int id;
        if (flags[0]) id = (int)((const long long*)idxRaw)[i];
        else          id = ((const int*)idxRaw)[i];
        sIdx[t] = id;
        const int mm = flags[1];
        bool mk;
        if      (mm == 0) mk = ((const unsigned char*)maskRaw)[i] != 0;
        else if (mm == 1) mk = ((const int*)maskRaw)[i] != 0;
        else              mk = ((const long long*)maskRaw)[i] != 0;
        sMask[t] = mk ? 1 : 0;
    }
    __syncthreads();

    // per-lane A row pointers: row mi*16+lm, element base lg*8
    const float* aptr[4];
    #pragma unroll
    for (int mi = 0; mi < 4; ++mi)
        aptr[mi] = table + (size_t)sIdx[mi * 16 + lm] * EE_ + lg * 8;

    // B-fragment base: W_t bf16, h = w*64 + ni*16 + lm, e = ks*32 + lg*8
    const unsigned short* wtB = WtBf + (size_t)(w * 64 + lm) * EE_ + lg * 8;

    f32x4 acc[4][4];
    #pragma unroll
    for (int mi = 0; mi < 4; ++mi)
        #pragma unroll
        for (int ni = 0; ni < 4; ++ni)
            acc[mi][ni] = (f32x4){0.f, 0.f, 0.f, 0.f};

    #pragma unroll 2
    for (int ks = 0; ks < 32; ++ks) {
        bf16x8 af[4];
        #pragma unroll
        for (int mi = 0; mi < 4; ++mi) {
            const f32x4 lo = *reinterpret_cast<const f32x4*>(aptr[mi] + ks * 32);
            const f32x4 hi = *reinterpret_cast<const f32x4*>(aptr[mi] + ks * 32 + 4);
            af[mi] = cvt8(lo, hi);
        }
        #pragma unroll
        for (int ni = 0; ni < 4; ++ni) {
            const bf16x8 bfr = *reinterpret_cast<const bf16x8*>(
                wtB + (size_t)ni * 16 * EE_ + ks * 32);
            #pragma unroll
            for (int mi = 0; mi < 4; ++mi)
                acc[mi][ni] = __builtin_amdgcn_mfma_f32_16x16x32_bf16(
                    af[mi], bfr, acc[mi][ni], 0, 0, 0);
        }
    }

    // Epilogue: masked max over 64 events per h column.
    // C/D layout: h = w*64 + ni*16 + lm; event = mi*16 + lg*4 + r
    #pragma unroll
    for (int ni = 0; ni < 4; ++ni) {
        float mx = -INFINITY;
        #pragma unroll
        for (int mi = 0; mi < 4; ++mi) {
            #pragma unroll
            for (int r = 0; r < 4; ++r) {
                const int ev = mi * 16 + lg * 4 + r;
                const float v = sMask[ev] ? acc[mi][ni][r] : -INFINITY;
                mx = fmaxf(mx, v);
            }
        }
        mx = fmaxf(mx, __shfl_xor(mx, 16));
        mx = fmaxf(mx, __shfl_xor(mx, 32));
        if (lg == 0) {
            const int h = w * 64 + ni * 16 + lm;
            sEv[h] = mx + bt[h];
        }
    }
    __syncthreads();

    // c[b][p] = sum_h ev_emb[h] * W_mm[p][h] + b_mm[p] + b_ts[p]   (wave 0)
    if (w == 0) {
        #pragma unroll 1
        for (int p = 0; p < PP; ++p) {
            const float* wr = Wmm + p * (HH + DD);
            float sum = sEv[l]       * wr[l]
                      + sEv[l + 64]  * wr[l + 64]
                      + sEv[l + 128] * wr[l + 128]
                      + sEv[l + 192] * wr[l + 192];
            #pragma unroll
            for (int off = 32; off >= 1; off >>= 1) sum += __shfl_xor(sum, off);
            if (l == 0) cOut[b * PP + p] = sum + bmm[p] + bts[p];
        }
    }
}

// ---------------------------------------------------------------------------
// ts path: R10 proven shape (256 thr, block = one batch, sequential 512KB
// stream) + explicit 2-chunk register ping-pong so 8 loads are ALWAYS in
// flight during each compute phase (breaks load->use serialization).
//   out[b][p][n] = 0.5 * (sum_d Wc[p][d]*ts[b][d][n] + c[b][p])
// ---------------------------------------------------------------------------
__global__ __launch_bounds__(256) void ts_kernel(
    const float* __restrict__ ts,
    const float* __restrict__ Wc,
    const float* __restrict__ cIn,
    float* __restrict__ out)
{
    const int b = blockIdx.x;
    const int t = threadIdx.x;

    __shared__ float sC[PP];
    __shared__ float sWc[PP * DD];
    if (t < PP) sC[t] = cIn[b * PP + t];
    for (int k = t; k < (PP * DD) / 4; k += 256)
        reinterpret_cast<float4*>(sWc)[k] = reinterpret_cast<const float4*>(Wc)[k];
    __syncthreads();

    const float* tsb = ts + (size_t)b * DD * NN + t * 4;

    f32x4 acc[PP];
    #pragma unroll
    for (int p = 0; p < PP; ++p) {
        const float c = sC[p];
        acc[p] = (f32x4){c, c, c, c};
    }

    f32x4 vA[8], vB[8];

    auto load8 = [&](f32x4 (&v)[8], int d0) {
        #pragma unroll
        for (int j = 0; j < 8; ++j)
            v[j] = *reinterpret_cast<const f32x4*>(tsb + (size_t)(d0 + j) * NN);
    };
    auto fma8 = [&](const f32x4 (&v)[8], int d0) {
        #pragma unroll
        for (int j = 0; j < 8; ++j) {
            #pragma unroll
            for (int p = 0; p < PP; ++p)
                acc[p] += sWc[p * DD + d0 + j] * v[j];   // LDS broadcast
        }
    };

    load8(vA, 0);
    #pragma unroll 1
    for (int d0 = 0; d0 < DD; d0 += 16) {
        load8(vB, d0 + 8);                 // 8 loads in flight...
        fma8(vA, d0);                      // ...under this compute
        if (d0 + 16 < DD) load8(vA, d0 + 16);
        fma8(vB, d0 + 8);
    }

    float* ob = out + (size_t)b * PP * NN + t * 4;
    #pragma unroll
    for (int p = 0; p < PP; ++p) {
        const f32x4 r = acc[p] * 0.5f;
        __builtin_nontemporal_store(r, reinterpret_cast<f32x4*>(ob + (size_t)p * NN));
    }
}

// ---------------------------------------------------------------------------
extern "C" void kernel_launch(void* const* d_in, const int* in_sizes, int n_in,
                              void* d_out, int out_size, void* d_ws, size_t ws_size,
                              hipStream_t stream)
{
    const float* ts    = (const float*)d_in[0];
    const float* table = (const float*)d_in[1];
    const float* Wt    = (const float*)d_in[2];
    const float* bt    = (const float*)d_in[3];
    const float* Wmm   = (const float*)d_in[4];
    const float* bmm   = (const float*)d_in[5];
    const float* Wts   = (const float*)d_in[6];
    const float* bts   = (const float*)d_in[7];
    const void*  idx   = (const void*)d_in[8];
    const void*  msk   = (const void*)d_in[9];
    float* out = (float*)d_out;

    // ws layout: [0, 512KB) W_t bf16; [512KB, +8KB) Wc; cB[512][12]; flags
    unsigned short* WtBf = (unsigned short*)d_ws;
    float* Wc  = (float*)((char*)d_ws + (512u << 10));
    float* cB  = (float*)((char*)d_ws + (512u << 10) + 8192);
    int*   flg = (int*)((char*)d_ws + (512u << 10) + 8192 + B_ * PP * 4);

    prep_kernel<<<257, 256, 0, stream>>>(Wt, Wmm, Wts,
                                         (const unsigned int*)idx,
                                         (const unsigned int*)msk,
                                         WtBf, Wc, flg);
    event_kernel<<<B_, 256, 0, stream>>>(table, idx, msk, flg, WtBf, bt,
                                         Wmm, bmm, bts, cB);
    ts_kernel<<<B_, 256, 0, stream>>>(ts, Wc, cB, out);
}